// Round 2
// baseline (6586.596 us; speedup 1.0000x reference)
//
#include <hip/hip_runtime.h>
#include <math.h>

#define WIDTH 256
#define PTS 8
#define ROWS 48          // 6 * PTS (rows: point*6 + {z, zx, zy, zt, zxx, zyy})
#define LSTR 50          // padded LDS row stride in floats; 256*50*4 = 51200 B -> 3 blocks/CU

// fast, well-conditioned tanh + sech^2: given u, returns z=tanh(u), s=1-z^2
// computed as s = 4t/(1+t)^2 with t=exp(-2|u|): no catastrophic cancellation
// in saturation (unlike 1-z*z), rel err ~1e-6.
__device__ __forceinline__ void tanh_s(float u, float& z, float& s) {
    const float t = __expf(-2.0f * fabsf(u));
    const float r = 1.0f / (1.0f + t);
    const float zm = (1.0f - t) * r;
    z = copysignf(zm, u);
    s = 4.0f * t * r * r;
}

__global__ __launch_bounds__(256, 3)
void pde_net_kernel(const float* __restrict__ xyt,
                    const float* __restrict__ w0, const float* __restrict__ b0,
                    const float* __restrict__ w1, const float* __restrict__ b1,
                    const float* __restrict__ w2, const float* __restrict__ b2,
                    const float* __restrict__ w3, const float* __restrict__ b3,
                    const float* __restrict__ w4, const float* __restrict__ b4,
                    const float* __restrict__ w5, const float* __restrict__ b5,
                    const float* __restrict__ w6, const float* __restrict__ b6,
                    float* __restrict__ out)
{
    // Z is feature-major: Z[j * LSTR + r], r = point*6 + vec.
    __shared__ float Z[WIDTH * LSTR];
    __shared__ float red[4 * ROWS];
    __shared__ float dvals[ROWS];
    __shared__ float pxyt[PTS * 3];

    const int tid = threadIdx.x;
    const int cg  = tid >> 3;      // 0..31 column group
    const int g   = tid & 7;       // 0..7  point-in-tile
    const int c0  = cg * 8;
    const int r0  = g * 6;
    const long gp0 = (long)blockIdx.x * PTS;

    if (tid < PTS * 3) pxyt[tid] = xyt[gp0 * 3 + tid];
    __syncthreads();

    // ---------------- layer 0: (3 -> 256) affine + tanh, 2nd-order forward mode ----
    {
        const float x = pxyt[g * 3 + 0];
        const float y = pxyt[g * 3 + 1];
        const float t = pxyt[g * 3 + 2];
        #pragma unroll
        for (int c = 0; c < 8; ++c) {
            const int j = c0 + c;
            const float wx = w0[0 * WIDTH + j];
            const float wy = w0[1 * WIDTH + j];
            const float wt = w0[2 * WIDTH + j];
            const float uz = fmaf(x, wx, fmaf(y, wy, fmaf(t, wt, b0[j])));
            float zv, s;
            tanh_s(uz, zv, s);
            float* zp = &Z[j * LSTR + r0];
            zp[0] = zv;                       // value
            zp[1] = s * wx;                   // d/dx
            zp[2] = s * wy;                   // d/dy
            zp[3] = s * wt;                   // d/dt
            zp[4] = -2.0f * zv * s * wx * wx; // d2/dx2 (u''=0)
            zp[5] = -2.0f * zv * s * wy * wy; // d2/dy2
        }
    }
    __syncthreads();

    // ---------------- hidden layers 1..5: (256 -> 256) affine + tanh ----------------
    const float* Ws[5] = { w1, w2, w3, w4, w5 };
    const float* Bs[5] = { b1, b2, b3, b4, b5 };

    for (int l = 0; l < 5; ++l) {
        const float* __restrict__ W = Ws[l];
        const float* __restrict__ B = Bs[l];

        float acc[6][8];
        #pragma unroll
        for (int v = 0; v < 6; ++v)
            #pragma unroll
            for (int c = 0; c < 8; ++c) acc[v][c] = 0.0f;

        // k-loop: unroll 8 so LDS/global addresses fold into immediate offsets.
        #pragma unroll 8
        for (int k = 0; k < WIDTH; ++k) {
            const float2 a01 = *(const float2*)&Z[k * LSTR + r0 + 0];
            const float2 a23 = *(const float2*)&Z[k * LSTR + r0 + 2];
            const float2 a45 = *(const float2*)&Z[k * LSTR + r0 + 4];
            const float4 wA  = *(const float4*)&W[k * WIDTH + c0 + 0];
            const float4 wB  = *(const float4*)&W[k * WIDTH + c0 + 4];
            const float a[6]  = { a01.x, a01.y, a23.x, a23.y, a45.x, a45.y };
            const float wv[8] = { wA.x, wA.y, wA.z, wA.w, wB.x, wB.y, wB.z, wB.w };
            #pragma unroll
            for (int v = 0; v < 6; ++v)
                #pragma unroll
                for (int c = 0; c < 8; ++c)
                    acc[v][c] = fmaf(a[v], wv[c], acc[v][c]);
        }
        __syncthreads();   // all reads of Z done before overwrite

        #pragma unroll
        for (int c = 0; c < 8; ++c) {
            const int j = c0 + c;
            const float uz = acc[0][c] + B[j];
            float zv, s;
            tanh_s(uz, zv, s);
            const float m2 = -2.0f * zv * s;
            float* zp = &Z[j * LSTR + r0];
            zp[0] = zv;
            zp[1] = s * acc[1][c];
            zp[2] = s * acc[2][c];
            zp[3] = s * acc[3][c];
            zp[4] = fmaf(m2 * acc[1][c], acc[1][c], s * acc[4][c]);
            zp[5] = fmaf(m2 * acc[2][c], acc[2][c], s * acc[5][c]);
        }
        __syncthreads();
    }

    // ---------------- final layer: (256 -> 1) dot products ----------------
    {
        const int r = tid & 63;
        const int chunk = tid >> 6;   // 0..3, 64 features each
        if (r < ROWS) {
            float partial = 0.0f;
            const int f0 = chunk * 64;
            #pragma unroll 8
            for (int f = 0; f < 64; ++f)
                partial = fmaf(Z[(f0 + f) * LSTR + r], w6[f0 + f], partial);
            red[chunk * ROWS + r] = partial;
        }
    }
    __syncthreads();
    if (tid < ROWS) {
        dvals[tid] = red[tid] + red[ROWS + tid] + red[2 * ROWS + tid] + red[3 * ROWS + tid];
    }
    __syncthreads();

    // ---------------- residual ----------------
    if (tid < PTS) {
        const int p = tid;
        const float h   = dvals[6 * p + 0] + b6[0];
        const float hx  = dvals[6 * p + 1];
        const float hy  = dvals[6 * p + 2];
        const float ht  = dvals[6 * p + 3];
        const float hxx = dvals[6 * p + 4];
        const float hyy = dvals[6 * p + 5];
        const float x = pxyt[p * 3 + 0];
        const float y = pxyt[p * 3 + 1];
        const float t = pxyt[p * 3 + 2];
        const float pi = 3.14159265358979323846f;
        const float f = sinf(pi * x) * sinf(pi * y) * expf(-t);
        // res = MU*ht - K*(h*(hxx+hyy) + hx^2 + hy^2) - f, MU=1, K=0.5
        const float res = ht - 0.5f * (h * (hxx + hyy) + hx * hx + hy * hy) - f;
        out[gp0 + p] = res;
    }
}

extern "C" void kernel_launch(void* const* d_in, const int* in_sizes, int n_in,
                              void* d_out, int out_size, void* d_ws, size_t ws_size,
                              hipStream_t stream) {
    const float* xyt = (const float*)d_in[0];
    const float* w0  = (const float*)d_in[1];
    const float* b0  = (const float*)d_in[2];
    const float* w1  = (const float*)d_in[3];
    const float* b1  = (const float*)d_in[4];
    const float* w2  = (const float*)d_in[5];
    const float* b2  = (const float*)d_in[6];
    const float* w3  = (const float*)d_in[7];
    const float* b3  = (const float*)d_in[8];
    const float* w4  = (const float*)d_in[9];
    const float* b4  = (const float*)d_in[10];
    const float* w5  = (const float*)d_in[11];
    const float* b5  = (const float*)d_in[12];
    const float* w6  = (const float*)d_in[13];
    const float* b6  = (const float*)d_in[14];
    float* out = (float*)d_out;

    const int npts = in_sizes[0] / 3;   // 131072
    dim3 grid(npts / PTS);
    dim3 block(256);
    pde_net_kernel<<<grid, block, 0, stream>>>(xyt, w0, b0, w1, b1, w2, b2,
                                               w3, b3, w4, b4, w5, b5, w6, b6, out);
}

// Round 3
// 6160.901 us; speedup vs baseline: 1.0691x; 1.0691x over previous
//
#include <hip/hip_runtime.h>
#include <math.h>

#define WIDTH 256
#define PTS 8
#define ROWS 48          // 6 * PTS (rows: point*6 + {z, zx, zy, zt, zxx, zyy})
#define LSTR 50          // padded LDS row stride in floats; 256*50*4 = 51200 B -> 3 blocks/CU

// fast, well-conditioned tanh + sech^2: z=tanh(u), s=1-z^2 = 4t/(1+t)^2, t=exp(-2|u|)
__device__ __forceinline__ void tanh_s(float u, float& z, float& s) {
    const float t = __expf(-2.0f * fabsf(u));
    const float r = 1.0f / (1.0f + t);
    const float zm = (1.0f - t) * r;
    z = copysignf(zm, u);
    s = 4.0f * t * r * r;
}

// 48 FMAs: acc[v][c] += a[v] * w[c]
__device__ __forceinline__ void fma48(float (&acc)[6][8],
                                      float2 a01, float2 a23, float2 a45,
                                      float4 wA, float4 wB) {
    const float av[6] = { a01.x, a01.y, a23.x, a23.y, a45.x, a45.y };
    const float wv[8] = { wA.x, wA.y, wA.z, wA.w, wB.x, wB.y, wB.z, wB.w };
    #pragma unroll
    for (int v = 0; v < 6; ++v)
        #pragma unroll
        for (int c = 0; c < 8; ++c)
            acc[v][c] = fmaf(av[v], wv[c], acc[v][c]);
}

__global__ __launch_bounds__(256, 3)
void pde_net_kernel(const float* __restrict__ xyt,
                    const float* __restrict__ w0, const float* __restrict__ b0,
                    const float* __restrict__ w1, const float* __restrict__ b1,
                    const float* __restrict__ w2, const float* __restrict__ b2,
                    const float* __restrict__ w3, const float* __restrict__ b3,
                    const float* __restrict__ w4, const float* __restrict__ b4,
                    const float* __restrict__ w5, const float* __restrict__ b5,
                    const float* __restrict__ w6, const float* __restrict__ b6,
                    float* __restrict__ out)
{
    // Z is feature-major: Z[j * LSTR + r], r = point*6 + vec.
    __shared__ float Z[WIDTH * LSTR];
    __shared__ float red[4 * ROWS];
    __shared__ float dvals[ROWS];
    __shared__ float pxyt[PTS * 3];

    const int tid = threadIdx.x;
    const int cg  = tid >> 3;      // 0..31 column group
    const int g   = tid & 7;       // 0..7  point-in-tile
    const int c0  = cg * 8;
    const int r0  = g * 6;
    const long gp0 = (long)blockIdx.x * PTS;

    if (tid < PTS * 3) pxyt[tid] = xyt[gp0 * 3 + tid];
    __syncthreads();

    // ---------------- layer 0: (3 -> 256) affine + tanh, 2nd-order forward mode ----
    {
        const float x = pxyt[g * 3 + 0];
        const float y = pxyt[g * 3 + 1];
        const float t = pxyt[g * 3 + 2];
        #pragma unroll
        for (int c = 0; c < 8; ++c) {
            const int j = c0 + c;
            const float wx = w0[0 * WIDTH + j];
            const float wy = w0[1 * WIDTH + j];
            const float wt = w0[2 * WIDTH + j];
            const float uz = fmaf(x, wx, fmaf(y, wy, fmaf(t, wt, b0[j])));
            float zv, s;
            tanh_s(uz, zv, s);
            float* zp = &Z[j * LSTR + r0];
            zp[0] = zv;                       // value
            zp[1] = s * wx;                   // d/dx
            zp[2] = s * wy;                   // d/dy
            zp[3] = s * wt;                   // d/dt
            zp[4] = -2.0f * zv * s * wx * wx; // d2/dx2 (u''=0)
            zp[5] = -2.0f * zv * s * wy * wy; // d2/dy2
        }
    }
    __syncthreads();

    // ---------------- hidden layers 1..5: (256 -> 256) affine + tanh ----------------
    const float* Ws[5] = { w1, w2, w3, w4, w5 };
    const float* Bs[5] = { b1, b2, b3, b4, b5 };

    for (int l = 0; l < 5; ++l) {
        const float* __restrict__ W = Ws[l];
        const float* __restrict__ B = Bs[l];

        float acc[6][8];
        #pragma unroll
        for (int v = 0; v < 6; ++v)
            #pragma unroll
            for (int c = 0; c < 8; ++c) acc[v][c] = 0.0f;

        // -------- explicit 2-deep software pipeline over k --------
        // invariant at loop top: stage A holds data for k
        float2 a0A = *(const float2*)&Z[0 * LSTR + r0 + 0];
        float2 a1A = *(const float2*)&Z[0 * LSTR + r0 + 2];
        float2 a2A = *(const float2*)&Z[0 * LSTR + r0 + 4];
        float4 wAA = *(const float4*)&W[0 * WIDTH + c0 + 0];
        float4 wBA = *(const float4*)&W[0 * WIDTH + c0 + 4];

        for (int k = 0; k <= WIDTH - 4; k += 2) {
            // issue loads for k+1 (stage B)
            float2 a0B = *(const float2*)&Z[(k + 1) * LSTR + r0 + 0];
            float2 a1B = *(const float2*)&Z[(k + 1) * LSTR + r0 + 2];
            float2 a2B = *(const float2*)&Z[(k + 1) * LSTR + r0 + 4];
            float4 wAB = *(const float4*)&W[(k + 1) * WIDTH + c0 + 0];
            float4 wBB = *(const float4*)&W[(k + 1) * WIDTH + c0 + 4];
            // compute k (stage A)
            fma48(acc, a0A, a1A, a2A, wAA, wBA);
            // issue loads for k+2 (stage A)
            a0A = *(const float2*)&Z[(k + 2) * LSTR + r0 + 0];
            a1A = *(const float2*)&Z[(k + 2) * LSTR + r0 + 2];
            a2A = *(const float2*)&Z[(k + 2) * LSTR + r0 + 4];
            wAA = *(const float4*)&W[(k + 2) * WIDTH + c0 + 0];
            wBA = *(const float4*)&W[(k + 2) * WIDTH + c0 + 4];
            // compute k+1 (stage B)
            fma48(acc, a0B, a1B, a2B, wAB, wBB);
        }
        // tail: stage A holds k = 254; load 255, compute both
        {
            float2 a0B = *(const float2*)&Z[255 * LSTR + r0 + 0];
            float2 a1B = *(const float2*)&Z[255 * LSTR + r0 + 2];
            float2 a2B = *(const float2*)&Z[255 * LSTR + r0 + 4];
            float4 wAB = *(const float4*)&W[255 * WIDTH + c0 + 0];
            float4 wBB = *(const float4*)&W[255 * WIDTH + c0 + 4];
            fma48(acc, a0A, a1A, a2A, wAA, wBA);
            fma48(acc, a0B, a1B, a2B, wAB, wBB);
        }
        __syncthreads();   // all reads of Z done before overwrite

        #pragma unroll
        for (int c = 0; c < 8; ++c) {
            const int j = c0 + c;
            const float uz = acc[0][c] + B[j];
            float zv, s;
            tanh_s(uz, zv, s);
            const float m2 = -2.0f * zv * s;
            float* zp = &Z[j * LSTR + r0];
            zp[0] = zv;
            zp[1] = s * acc[1][c];
            zp[2] = s * acc[2][c];
            zp[3] = s * acc[3][c];
            zp[4] = fmaf(m2 * acc[1][c], acc[1][c], s * acc[4][c]);
            zp[5] = fmaf(m2 * acc[2][c], acc[2][c], s * acc[5][c]);
        }
        __syncthreads();
    }

    // ---------------- final layer: (256 -> 1) dot products ----------------
    {
        const int r = tid & 63;
        const int chunk = tid >> 6;   // 0..3, 64 features each
        if (r < ROWS) {
            float partial = 0.0f;
            const int f0 = chunk * 64;
            #pragma unroll 8
            for (int f = 0; f < 64; ++f)
                partial = fmaf(Z[(f0 + f) * LSTR + r], w6[f0 + f], partial);
            red[chunk * ROWS + r] = partial;
        }
    }
    __syncthreads();
    if (tid < ROWS) {
        dvals[tid] = red[tid] + red[ROWS + tid] + red[2 * ROWS + tid] + red[3 * ROWS + tid];
    }
    __syncthreads();

    // ---------------- residual ----------------
    if (tid < PTS) {
        const int p = tid;
        const float h   = dvals[6 * p + 0] + b6[0];
        const float hx  = dvals[6 * p + 1];
        const float hy  = dvals[6 * p + 2];
        const float ht  = dvals[6 * p + 3];
        const float hxx = dvals[6 * p + 4];
        const float hyy = dvals[6 * p + 5];
        const float x = pxyt[p * 3 + 0];
        const float y = pxyt[p * 3 + 1];
        const float t = pxyt[p * 3 + 2];
        const float pi = 3.14159265358979323846f;
        const float f = sinf(pi * x) * sinf(pi * y) * expf(-t);
        // res = MU*ht - K*(h*(hxx+hyy) + hx^2 + hy^2) - f, MU=1, K=0.5
        const float res = ht - 0.5f * (h * (hxx + hyy) + hx * hx + hy * hy) - f;
        out[gp0 + p] = res;
    }
}

extern "C" void kernel_launch(void* const* d_in, const int* in_sizes, int n_in,
                              void* d_out, int out_size, void* d_ws, size_t ws_size,
                              hipStream_t stream) {
    const float* xyt = (const float*)d_in[0];
    const float* w0  = (const float*)d_in[1];
    const float* b0  = (const float*)d_in[2];
    const float* w1  = (const float*)d_in[3];
    const float* b1  = (const float*)d_in[4];
    const float* w2  = (const float*)d_in[5];
    const float* b2  = (const float*)d_in[6];
    const float* w3  = (const float*)d_in[7];
    const float* b3  = (const float*)d_in[8];
    const float* w4  = (const float*)d_in[9];
    const float* b4  = (const float*)d_in[10];
    const float* w5  = (const float*)d_in[11];
    const float* b5  = (const float*)d_in[12];
    const float* w6  = (const float*)d_in[13];
    const float* b6  = (const float*)d_in[14];
    float* out = (float*)d_out;

    const int npts = in_sizes[0] / 3;   // 131072
    dim3 grid(npts / PTS);
    dim3 block(256);
    pde_net_kernel<<<grid, block, 0, stream>>>(xyt, w0, b0, w1, b1, w2, b2,
                                               w3, b3, w4, b4, w5, b5, w6, b6, out);
}

// Round 4
// 5502.871 us; speedup vs baseline: 1.1969x; 1.1196x over previous
//
#include <hip/hip_runtime.h>
#include <math.h>

#define WIDTH 256
#define PTS 8
#define NVEC 5           // z, zx, zy, zt, L  (L = laplacian_{xy} chain)
#define PLANE (WIDTH * PTS)   // 2048 floats per vector plane

// fast, well-conditioned tanh + sech^2: z=tanh(u), s=1-z^2 = 4t/(1+t)^2, t=exp(-2|u|)
__device__ __forceinline__ void tanh_s(float u, float& z, float& s) {
    const float t = __expf(-2.0f * fabsf(u));
    const float r = 1.0f / (1.0f + t);
    const float zm = (1.0f - t) * r;
    z = copysignf(zm, u);
    s = 4.0f * t * r * r;
}

__global__ __launch_bounds__(256, 4)
void pde_net_kernel(const float* __restrict__ xyt,
                    const float* __restrict__ w0, const float* __restrict__ b0,
                    const float* __restrict__ w1, const float* __restrict__ b1,
                    const float* __restrict__ w2, const float* __restrict__ b2,
                    const float* __restrict__ w3, const float* __restrict__ b3,
                    const float* __restrict__ w4, const float* __restrict__ b4,
                    const float* __restrict__ w5, const float* __restrict__ b5,
                    const float* __restrict__ w6, const float* __restrict__ b6,
                    float* __restrict__ out)
{
    // Z[v][k][p]: vector-plane SoA. 5*256*8*4 = 40960 B exactly -> 4 blocks/CU.
    // Final-layer reduction scratch is aliased into Z after its last full read.
    __shared__ float Z[NVEC * PLANE];

    const int tid = threadIdx.x;
    const int cg  = tid >> 3;      // 0..31 column group
    const int g   = tid & 7;       // 0..7  point-in-tile
    const int c0  = cg * 8;
    const long gp0 = (long)blockIdx.x * PTS;

    // ---------------- layer 0: (3 -> 256) affine + tanh, Taylor-mode ----
    {
        const float x = xyt[(gp0 + g) * 3 + 0];
        const float y = xyt[(gp0 + g) * 3 + 1];
        const float t = xyt[(gp0 + g) * 3 + 2];
        #pragma unroll
        for (int c = 0; c < 8; ++c) {
            const int j = c0 + c;
            const float wx = w0[0 * WIDTH + j];
            const float wy = w0[1 * WIDTH + j];
            const float wt = w0[2 * WIDTH + j];
            const float uz = fmaf(x, wx, fmaf(y, wy, fmaf(t, wt, b0[j])));
            float zv, s;
            tanh_s(uz, zv, s);
            const int base = j * PTS + g;
            Z[0 * PLANE + base] = zv;                                  // value
            Z[1 * PLANE + base] = s * wx;                              // d/dx
            Z[2 * PLANE + base] = s * wy;                              // d/dy
            Z[3 * PLANE + base] = s * wt;                              // d/dt
            Z[4 * PLANE + base] = -2.0f * zv * s * (wx * wx + wy * wy); // laplacian_xy
        }
    }
    __syncthreads();

    // ---------------- hidden layers 1..5: (256 -> 256) affine + tanh ------
    const float* Ws[5] = { w1, w2, w3, w4, w5 };
    const float* Bs[5] = { b1, b2, b3, b4, b5 };

    for (int l = 0; l < 5; ++l) {
        const float* __restrict__ W = Ws[l];
        const float* __restrict__ B = Bs[l];

        float acc[NVEC][8];
        #pragma unroll
        for (int v = 0; v < NVEC; ++v)
            #pragma unroll
            for (int c = 0; c < 8; ++c) acc[v][c] = 0.0f;

        #pragma unroll 4
        for (int k = 0; k < WIDTH; ++k) {
            const int zb = k * PTS + g;
            const float a0 = Z[0 * PLANE + zb];
            const float a1 = Z[1 * PLANE + zb];
            const float a2 = Z[2 * PLANE + zb];
            const float a3 = Z[3 * PLANE + zb];
            const float a4 = Z[4 * PLANE + zb];
            const float4 wA = *(const float4*)&W[k * WIDTH + c0 + 0];
            const float4 wB = *(const float4*)&W[k * WIDTH + c0 + 4];
            const float wv[8] = { wA.x, wA.y, wA.z, wA.w, wB.x, wB.y, wB.z, wB.w };
            #pragma unroll
            for (int c = 0; c < 8; ++c) {
                acc[0][c] = fmaf(a0, wv[c], acc[0][c]);
                acc[1][c] = fmaf(a1, wv[c], acc[1][c]);
                acc[2][c] = fmaf(a2, wv[c], acc[2][c]);
                acc[3][c] = fmaf(a3, wv[c], acc[3][c]);
                acc[4][c] = fmaf(a4, wv[c], acc[4][c]);
            }
        }
        __syncthreads();   // all reads of Z done before overwrite

        #pragma unroll
        for (int c = 0; c < 8; ++c) {
            const int j = c0 + c;
            const float uz = acc[0][c] + B[j];
            float zv, s;
            tanh_s(uz, zv, s);
            const float ux = acc[1][c];
            const float uy = acc[2][c];
            const float m2 = -2.0f * zv * s;
            const int base = j * PTS + g;
            Z[0 * PLANE + base] = zv;
            Z[1 * PLANE + base] = s * ux;
            Z[2 * PLANE + base] = s * uy;
            Z[3 * PLANE + base] = s * acc[3][c];
            Z[4 * PLANE + base] = fmaf(m2, fmaf(ux, ux, uy * uy), s * acc[4][c]);
        }
        __syncthreads();
    }

    // ---------------- final layer: (256 -> 1) dot products -----------------
    // 40 rows (v*8+p), 4 feature-chunks of 64. Scratch aliased into Z after
    // the last read of Z completes (guarded by barriers).
    float partial = 0.0f;
    const int r = tid & 63;
    const int chunk = tid >> 6;      // 0..3
    const int rv = r >> 3;           // 0..4 (valid when r < 40)
    const int rp = r & 7;
    if (r < NVEC * PTS) {
        const int f0 = chunk * 64;
        #pragma unroll 8
        for (int f = 0; f < 64; ++f)
            partial = fmaf(Z[rv * PLANE + (f0 + f) * PTS + rp], w6[f0 + f], partial);
    }
    __syncthreads();                 // all reads of Z done
    if (r < NVEC * PTS) Z[chunk * 40 + r] = partial;
    __syncthreads();
    if (tid < NVEC * PTS) {
        Z[160 + tid] = Z[tid] + Z[40 + tid] + Z[80 + tid] + Z[120 + tid];
    }
    __syncthreads();

    // ---------------- residual ----------------
    if (tid < PTS) {
        const int p = tid;
        const float h   = Z[160 + 0 * 8 + p] + b6[0];
        const float hx  = Z[160 + 1 * 8 + p];
        const float hy  = Z[160 + 2 * 8 + p];
        const float ht  = Z[160 + 3 * 8 + p];
        const float lap = Z[160 + 4 * 8 + p];
        const float x = xyt[(gp0 + p) * 3 + 0];
        const float y = xyt[(gp0 + p) * 3 + 1];
        const float t = xyt[(gp0 + p) * 3 + 2];
        const float pi = 3.14159265358979323846f;
        const float f = sinf(pi * x) * sinf(pi * y) * expf(-t);
        // res = MU*ht - K*(h*lap + hx^2 + hy^2) - f, MU=1, K=0.5
        const float res = ht - 0.5f * (fmaf(h, lap, fmaf(hx, hx, hy * hy))) - f;
        out[gp0 + p] = res;
    }
}

extern "C" void kernel_launch(void* const* d_in, const int* in_sizes, int n_in,
                              void* d_out, int out_size, void* d_ws, size_t ws_size,
                              hipStream_t stream) {
    const float* xyt = (const float*)d_in[0];
    const float* w0  = (const float*)d_in[1];
    const float* b0  = (const float*)d_in[2];
    const float* w1  = (const float*)d_in[3];
    const float* b1  = (const float*)d_in[4];
    const float* w2  = (const float*)d_in[5];
    const float* b2  = (const float*)d_in[6];
    const float* w3  = (const float*)d_in[7];
    const float* b3  = (const float*)d_in[8];
    const float* w4  = (const float*)d_in[9];
    const float* b4  = (const float*)d_in[10];
    const float* w5  = (const float*)d_in[11];
    const float* b5  = (const float*)d_in[12];
    const float* w6  = (const float*)d_in[13];
    const float* b6  = (const float*)d_in[14];
    float* out = (float*)d_out;

    const int npts = in_sizes[0] / 3;   // 131072
    dim3 grid(npts / PTS);
    dim3 block(256);
    pde_net_kernel<<<grid, block, 0, stream>>>(xyt, w0, b0, w1, b1, w2, b2,
                                               w3, b3, w4, b4, w5, b5, w6, b6, out);
}

// Round 5
// 5273.001 us; speedup vs baseline: 1.2491x; 1.0436x over previous
//
#include <hip/hip_runtime.h>
#include <math.h>

#define WIDTH 256
#define PTS 8
#define NVEC 5            // z, zx, zy, zt, L (fused xy-laplacian chain)
#define QPLANE 512        // float4 slots per plane = 256*8/4; 5 planes * 8192 B = 40960 B

// fast, well-conditioned tanh + sech^2: z=tanh(u), s=1-z^2 = 4t/(1+t)^2, t=exp(-2|u|)
__device__ __forceinline__ void tanh_s(float u, float& z, float& s) {
    const float t = __expf(-2.0f * fabsf(u));
    const float r = 1.0f / (1.0f + t);
    const float zm = (1.0f - t) * r;
    z = copysignf(zm, u);
    s = 4.0f * t * r * r;
}

// 40 FMAs: acc[v][c] += b_v * wc[c]
__device__ __forceinline__ void fma40(float (&acc)[NVEC][8],
                                      float b0, float b1, float b2, float b3, float b4,
                                      const float4 wA, const float4 wB) {
    const float wc[8] = { wA.x, wA.y, wA.z, wA.w, wB.x, wB.y, wB.z, wB.w };
    #pragma unroll
    for (int c = 0; c < 8; ++c) {
        acc[0][c] = fmaf(b0, wc[c], acc[0][c]);
        acc[1][c] = fmaf(b1, wc[c], acc[1][c]);
        acc[2][c] = fmaf(b2, wc[c], acc[2][c]);
        acc[3][c] = fmaf(b3, wc[c], acc[3][c]);
        acc[4][c] = fmaf(b4, wc[c], acc[4][c]);
    }
}

__global__ __launch_bounds__(256, 4)
void pde_net_kernel(const float* __restrict__ xyt,
                    const float* __restrict__ w0, const float* __restrict__ b0,
                    const float* __restrict__ w1, const float* __restrict__ b1,
                    const float* __restrict__ w2, const float* __restrict__ b2,
                    const float* __restrict__ w3, const float* __restrict__ b3,
                    const float* __restrict__ w4, const float* __restrict__ b4,
                    const float* __restrict__ w5, const float* __restrict__ b5,
                    const float* __restrict__ w6, const float* __restrict__ b6,
                    float* __restrict__ out)
{
    // Z4[v*QPLANE + g*64 + (kq ^ g)] holds features 4kq..4kq+3 of vector v, point g.
    // XOR swizzle: the 8 g-rows tile the 32 banks (bank base = ((kq^g)%8)*4) ->
    // conflict-free broadcast reads in the k-loop; writes hit the 8-cycle data floor.
    __shared__ float4 Z4[NVEC * QPLANE];     // 40960 B exactly -> 4 blocks/CU
    float* Zf = (float*)Z4;

    const int tid = threadIdx.x;
    const int cg  = tid >> 3;      // 0..31 column group (features c0..c0+7)
    const int g   = tid & 7;       // 0..7  point-in-tile
    const int c0  = cg * 8;
    const int gbase = g * 64;      // float4 row base
    const long gp0 = (long)blockIdx.x * PTS;

    // ---------------- layer 0: (3 -> 256) affine + tanh, Taylor-mode ----
    {
        const float x = xyt[(gp0 + g) * 3 + 0];
        const float y = xyt[(gp0 + g) * 3 + 1];
        const float t = xyt[(gp0 + g) * 3 + 2];
        float obuf[NVEC][8];
        #pragma unroll
        for (int c = 0; c < 8; ++c) {
            const int j = c0 + c;
            const float wx = w0[0 * WIDTH + j];
            const float wy = w0[1 * WIDTH + j];
            const float wt = w0[2 * WIDTH + j];
            const float uz = fmaf(x, wx, fmaf(y, wy, fmaf(t, wt, b0[j])));
            float zv, s;
            tanh_s(uz, zv, s);
            obuf[0][c] = zv;
            obuf[1][c] = s * wx;
            obuf[2][c] = s * wy;
            obuf[3][c] = s * wt;
            obuf[4][c] = -2.0f * zv * s * (wx * wx + wy * wy);
        }
        #pragma unroll
        for (int v = 0; v < NVEC; ++v) {
            Z4[v * QPLANE + gbase + ((cg * 2 + 0) ^ g)] =
                make_float4(obuf[v][0], obuf[v][1], obuf[v][2], obuf[v][3]);
            Z4[v * QPLANE + gbase + ((cg * 2 + 1) ^ g)] =
                make_float4(obuf[v][4], obuf[v][5], obuf[v][6], obuf[v][7]);
        }
    }
    __syncthreads();

    // ---------------- hidden layers 1..5: (256 -> 256) affine + tanh ------
    const float* Ws[5] = { w1, w2, w3, w4, w5 };
    const float* Bs[5] = { b1, b2, b3, b4, b5 };

    for (int l = 0; l < 5; ++l) {
        const float* __restrict__ W = Ws[l];
        const float* __restrict__ B = Bs[l];

        float acc[NVEC][8];
        #pragma unroll
        for (int v = 0; v < NVEC; ++v)
            #pragma unroll
            for (int c = 0; c < 8; ++c) acc[v][c] = 0.0f;

        const float4* __restrict__ Zg = Z4 + gbase;
        const float*  __restrict__ Wc = W + c0;

        for (int kq = 0; kq < 64; ++kq) {      // 4 features per iteration
            const int t = kq ^ g;
            const float4 a0 = Zg[0 * QPLANE + t];
            const float4 a1 = Zg[1 * QPLANE + t];
            const float4 a2 = Zg[2 * QPLANE + t];
            const float4 a3 = Zg[3 * QPLANE + t];
            const float4 a4 = Zg[4 * QPLANE + t];
            const float* Wk = Wc + kq * 4 * WIDTH;
            const float4 w0A = *(const float4*)(Wk + 0 * WIDTH + 0);
            const float4 w0B = *(const float4*)(Wk + 0 * WIDTH + 4);
            const float4 w1A = *(const float4*)(Wk + 1 * WIDTH + 0);
            const float4 w1B = *(const float4*)(Wk + 1 * WIDTH + 4);
            const float4 w2A = *(const float4*)(Wk + 2 * WIDTH + 0);
            const float4 w2B = *(const float4*)(Wk + 2 * WIDTH + 4);
            const float4 w3A = *(const float4*)(Wk + 3 * WIDTH + 0);
            const float4 w3B = *(const float4*)(Wk + 3 * WIDTH + 4);
            fma40(acc, a0.x, a1.x, a2.x, a3.x, a4.x, w0A, w0B);
            fma40(acc, a0.y, a1.y, a2.y, a3.y, a4.y, w1A, w1B);
            fma40(acc, a0.z, a1.z, a2.z, a3.z, a4.z, w2A, w2B);
            fma40(acc, a0.w, a1.w, a2.w, a3.w, a4.w, w3A, w3B);
        }
        __syncthreads();   // all reads of Z done before overwrite

        float obuf[NVEC][8];
        #pragma unroll
        for (int c = 0; c < 8; ++c) {
            const float uz = acc[0][c] + B[c0 + c];
            float zv, s;
            tanh_s(uz, zv, s);
            const float ux = acc[1][c];
            const float uy = acc[2][c];
            const float m2 = -2.0f * zv * s;
            obuf[0][c] = zv;
            obuf[1][c] = s * ux;
            obuf[2][c] = s * uy;
            obuf[3][c] = s * acc[3][c];
            obuf[4][c] = fmaf(m2, fmaf(ux, ux, uy * uy), s * acc[4][c]);
        }
        #pragma unroll
        for (int v = 0; v < NVEC; ++v) {
            Z4[v * QPLANE + gbase + ((cg * 2 + 0) ^ g)] =
                make_float4(obuf[v][0], obuf[v][1], obuf[v][2], obuf[v][3]);
            Z4[v * QPLANE + gbase + ((cg * 2 + 1) ^ g)] =
                make_float4(obuf[v][4], obuf[v][5], obuf[v][6], obuf[v][7]);
        }
        __syncthreads();
    }

    // ---------------- final layer: (256 -> 1) dot products -----------------
    // 40 rows (v*8+p), 4 feature-chunks of 64 floats (16 float4 slots each).
    float partial = 0.0f;
    const int r = tid & 63;
    const int chunk = tid >> 6;      // 0..3
    const int rv = r >> 3;           // 0..4 (valid when r < 40)
    const int rp = r & 7;
    if (r < NVEC * PTS) {
        const int f0q = chunk * 16;
        #pragma unroll 4
        for (int fq = 0; fq < 16; ++fq) {
            const float4 zq = Z4[rv * QPLANE + rp * 64 + ((f0q + fq) ^ rp)];
            const float4 wq = *(const float4*)&w6[(f0q + fq) * 4];
            partial = fmaf(zq.x, wq.x, partial);
            partial = fmaf(zq.y, wq.y, partial);
            partial = fmaf(zq.z, wq.z, partial);
            partial = fmaf(zq.w, wq.w, partial);
        }
    }
    __syncthreads();                 // all reads of Z done
    if (r < NVEC * PTS) Zf[chunk * 40 + r] = partial;
    __syncthreads();
    if (tid < NVEC * PTS) {
        Zf[160 + tid] = Zf[tid] + Zf[40 + tid] + Zf[80 + tid] + Zf[120 + tid];
    }
    __syncthreads();

    // ---------------- residual ----------------
    if (tid < PTS) {
        const int p = tid;
        const float h   = Zf[160 + 0 * 8 + p] + b6[0];
        const float hx  = Zf[160 + 1 * 8 + p];
        const float hy  = Zf[160 + 2 * 8 + p];
        const float ht  = Zf[160 + 3 * 8 + p];
        const float lap = Zf[160 + 4 * 8 + p];
        const float x = xyt[(gp0 + p) * 3 + 0];
        const float y = xyt[(gp0 + p) * 3 + 1];
        const float t = xyt[(gp0 + p) * 3 + 2];
        const float pi = 3.14159265358979323846f;
        const float f = sinf(pi * x) * sinf(pi * y) * expf(-t);
        // res = MU*ht - K*(h*lap + hx^2 + hy^2) - f, MU=1, K=0.5
        const float res = ht - 0.5f * (fmaf(h, lap, fmaf(hx, hx, hy * hy))) - f;
        out[gp0 + p] = res;
    }
}

extern "C" void kernel_launch(void* const* d_in, const int* in_sizes, int n_in,
                              void* d_out, int out_size, void* d_ws, size_t ws_size,
                              hipStream_t stream) {
    const float* xyt = (const float*)d_in[0];
    const float* w0  = (const float*)d_in[1];
    const float* b0  = (const float*)d_in[2];
    const float* w1  = (const float*)d_in[3];
    const float* b1  = (const float*)d_in[4];
    const float* w2  = (const float*)d_in[5];
    const float* b2  = (const float*)d_in[6];
    const float* w3  = (const float*)d_in[7];
    const float* b3  = (const float*)d_in[8];
    const float* w4  = (const float*)d_in[9];
    const float* b4  = (const float*)d_in[10];
    const float* w5  = (const float*)d_in[11];
    const float* b5  = (const float*)d_in[12];
    const float* w6  = (const float*)d_in[13];
    const float* b6  = (const float*)d_in[14];
    float* out = (float*)d_out;

    const int npts = in_sizes[0] / 3;   // 131072
    dim3 grid(npts / PTS);
    dim3 block(256);
    pde_net_kernel<<<grid, block, 0, stream>>>(xyt, w0, b0, w1, b1, w2, b2,
                                               w3, b3, w4, b4, w5, b5, w6, b6, out);
}

// Round 6
// 4600.547 us; speedup vs baseline: 1.4317x; 1.1462x over previous
//
#include <hip/hip_runtime.h>
#include <math.h>

#define WIDTH 256
#define PTS 16
#define NVEC 5            // z, zx, zy, zt, L (fused xy-laplacian chain)
#define QP_PLANE 1024     // float4 slots/plane: 8 point-pairs * 128 k-pairs; 5 planes = 81920 B

// fast, well-conditioned tanh + sech^2: z=tanh(u), s=1-z^2 = 4t/(1+t)^2, t=exp(-2|u|)
__device__ __forceinline__ void tanh_s(float u, float& z, float& s) {
    const float t = __expf(-2.0f * fabsf(u));
    const float r = 1.0f / (1.0f + t);
    const float zm = (1.0f - t) * r;
    z = copysignf(zm, u);
    s = 4.0f * t * r * r;
}

// 160 FMAs: two k-steps for 8 cols x 2 points x 5 vecs.
// a_v = (k0,p0),(k0,p1),(k1,p0),(k1,p1); w0*/w1* = W[k0][c0..+7], W[k1][c0..+7]
__device__ __forceinline__ void fma160(float (&acc)[NVEC][8][2],
                                       const float4 a0, const float4 a1, const float4 a2,
                                       const float4 a3, const float4 a4,
                                       const float4 w0A, const float4 w0B,
                                       const float4 w1A, const float4 w1B) {
    const float wc0[8] = { w0A.x, w0A.y, w0A.z, w0A.w, w0B.x, w0B.y, w0B.z, w0B.w };
    const float wc1[8] = { w1A.x, w1A.y, w1A.z, w1A.w, w1B.x, w1B.y, w1B.z, w1B.w };
    const float4 av[NVEC] = { a0, a1, a2, a3, a4 };
    #pragma unroll
    for (int v = 0; v < NVEC; ++v) {
        #pragma unroll
        for (int c = 0; c < 8; ++c) {
            acc[v][c][0] = fmaf(av[v].x, wc0[c], acc[v][c][0]);
            acc[v][c][1] = fmaf(av[v].y, wc0[c], acc[v][c][1]);
            acc[v][c][0] = fmaf(av[v].z, wc1[c], acc[v][c][0]);
            acc[v][c][1] = fmaf(av[v].w, wc1[c], acc[v][c][1]);
        }
    }
}

__global__ __launch_bounds__(256, 2)
void pde_net_kernel(const float* __restrict__ xyt,
                    const float* __restrict__ w0, const float* __restrict__ b0,
                    const float* __restrict__ w1, const float* __restrict__ b1,
                    const float* __restrict__ w2, const float* __restrict__ b2,
                    const float* __restrict__ w3, const float* __restrict__ b3,
                    const float* __restrict__ w4, const float* __restrict__ b4,
                    const float* __restrict__ w5, const float* __restrict__ b5,
                    const float* __restrict__ w6, const float* __restrict__ b6,
                    float* __restrict__ out)
{
    // Slot (v, pp, q): float4 = vec v at (k=2q,p=2pp),(2q,2pp+1),(2q+1,2pp),(2q+1,2pp+1),
    // stored at Z4[v*QP_PLANE + pp*128 + (q ^ pp)]. XOR swizzle -> conflict-free k-loop
    // reads (8 distinct pp -> 8 distinct bank groups), epilogue writes at the data floor.
    __shared__ float4 Z4[NVEC * QP_PLANE];   // 81920 B exactly -> 2 blocks/CU
    float* Zf = (float*)Z4;

    const int tid = threadIdx.x;
    const int cg  = tid >> 3;        // 0..31 column group (cols c0..c0+7)
    const int pp  = tid & 7;         // 0..7 point-pair
    const int c0  = cg * 8;
    const long gp0 = (long)blockIdx.x * PTS;
    const int p0 = pp * 2, p1 = p0 + 1;

    // ---------------- layer 0: (3 -> 256) affine + tanh, Taylor-mode ----
    {
        const float x0 = xyt[(gp0 + p0) * 3 + 0];
        const float y0 = xyt[(gp0 + p0) * 3 + 1];
        const float t0 = xyt[(gp0 + p0) * 3 + 2];
        const float x1 = xyt[(gp0 + p1) * 3 + 0];
        const float y1 = xyt[(gp0 + p1) * 3 + 1];
        const float t1 = xyt[(gp0 + p1) * 3 + 2];
        float ob[NVEC][8][2];
        #pragma unroll
        for (int c = 0; c < 8; ++c) {
            const int j = c0 + c;
            const float wx = w0[0 * WIDTH + j];
            const float wy = w0[1 * WIDTH + j];
            const float wt = w0[2 * WIDTH + j];
            const float bb = b0[j];
            const float ww = wx * wx + wy * wy;
            float zv, s;
            tanh_s(fmaf(x0, wx, fmaf(y0, wy, fmaf(t0, wt, bb))), zv, s);
            ob[0][c][0] = zv;  ob[1][c][0] = s * wx;  ob[2][c][0] = s * wy;
            ob[3][c][0] = s * wt;  ob[4][c][0] = -2.0f * zv * s * ww;
            tanh_s(fmaf(x1, wx, fmaf(y1, wy, fmaf(t1, wt, bb))), zv, s);
            ob[0][c][1] = zv;  ob[1][c][1] = s * wx;  ob[2][c][1] = s * wy;
            ob[3][c][1] = s * wt;  ob[4][c][1] = -2.0f * zv * s * ww;
        }
        #pragma unroll
        for (int v = 0; v < NVEC; ++v)
            #pragma unroll
            for (int i = 0; i < 4; ++i)
                Z4[v * QP_PLANE + pp * 128 + ((cg * 4 + i) ^ pp)] =
                    make_float4(ob[v][2 * i][0], ob[v][2 * i][1],
                                ob[v][2 * i + 1][0], ob[v][2 * i + 1][1]);
    }
    __syncthreads();

    // ---------------- hidden layers 1..5: (256 -> 256) affine + tanh ------
    const float* Ws[5] = { w1, w2, w3, w4, w5 };
    const float* Bs[5] = { b1, b2, b3, b4, b5 };

    for (int l = 0; l < 5; ++l) {
        const float* __restrict__ W = Ws[l];
        const float* __restrict__ B = Bs[l];

        float acc[NVEC][8][2];
        #pragma unroll
        for (int v = 0; v < NVEC; ++v)
            #pragma unroll
            for (int c = 0; c < 8; ++c)
                acc[v][c][0] = acc[v][c][1] = 0.0f;

        const float4* __restrict__ Zp = Z4 + pp * 128;
        const float*  __restrict__ Wc = W + c0;

        #pragma unroll 2
        for (int q = 0; q < 128; ++q) {       // two k's per iteration
            const int slot = q ^ pp;
            const float4 a0 = Zp[0 * QP_PLANE + slot];
            const float4 a1 = Zp[1 * QP_PLANE + slot];
            const float4 a2 = Zp[2 * QP_PLANE + slot];
            const float4 a3 = Zp[3 * QP_PLANE + slot];
            const float4 a4 = Zp[4 * QP_PLANE + slot];
            const float* Wk = Wc + 2 * q * WIDTH;
            const float4 w0A = *(const float4*)(Wk + 0);
            const float4 w0B = *(const float4*)(Wk + 4);
            const float4 w1A = *(const float4*)(Wk + WIDTH + 0);
            const float4 w1B = *(const float4*)(Wk + WIDTH + 4);
            fma160(acc, a0, a1, a2, a3, a4, w0A, w0B, w1A, w1B);
        }
        __syncthreads();   // all reads of Z done before overwrite

        float ob[NVEC][8][2];
        #pragma unroll
        for (int c = 0; c < 8; ++c) {
            const float bb = B[c0 + c];
            #pragma unroll
            for (int p = 0; p < 2; ++p) {
                float zv, s;
                tanh_s(acc[0][c][p] + bb, zv, s);
                const float ux = acc[1][c][p];
                const float uy = acc[2][c][p];
                const float m2 = -2.0f * zv * s;
                ob[0][c][p] = zv;
                ob[1][c][p] = s * ux;
                ob[2][c][p] = s * uy;
                ob[3][c][p] = s * acc[3][c][p];
                ob[4][c][p] = fmaf(m2, fmaf(ux, ux, uy * uy), s * acc[4][c][p]);
            }
        }
        #pragma unroll
        for (int v = 0; v < NVEC; ++v)
            #pragma unroll
            for (int i = 0; i < 4; ++i)
                Z4[v * QP_PLANE + pp * 128 + ((cg * 4 + i) ^ pp)] =
                    make_float4(ob[v][2 * i][0], ob[v][2 * i][1],
                                ob[v][2 * i + 1][0], ob[v][2 * i + 1][1]);
        __syncthreads();
    }

    // ---------------- final layer: (256 -> 1) dot products -----------------
    // 80 rows (v*16+p), 2 halves of 128 features each.
    float partial = 0.0f;
    const int half = tid >> 7;       // 0..1
    const int r    = tid & 127;      // row if < 80
    const int rv   = r >> 4;         // 0..4
    const int rp   = r & 15;         // 0..15
    const int rpp  = rp >> 1;
    const int odd  = rp & 1;
    if (r < NVEC * PTS) {
        const float4* Zr = Z4 + rv * QP_PLANE + rpp * 128;
        #pragma unroll 4
        for (int i = 0; i < 64; ++i) {
            const int q = half * 64 + i;
            const float4 zq = Zr[q ^ rpp];
            const float2 wq = *(const float2*)&w6[q * 2];
            const float za = odd ? zq.y : zq.x;
            const float zb = odd ? zq.w : zq.z;
            partial = fmaf(za, wq.x, fmaf(zb, wq.y, partial));
        }
    }
    __syncthreads();                 // all reads of Z done
    if (r < NVEC * PTS) Zf[half * 80 + r] = partial;
    __syncthreads();
    if (tid < NVEC * PTS) Zf[160 + tid] = Zf[tid] + Zf[80 + tid];
    __syncthreads();

    // ---------------- residual ----------------
    if (tid < PTS) {
        const int p = tid;
        const float h   = Zf[160 + 0 * PTS + p] + b6[0];
        const float hx  = Zf[160 + 1 * PTS + p];
        const float hy  = Zf[160 + 2 * PTS + p];
        const float ht  = Zf[160 + 3 * PTS + p];
        const float lap = Zf[160 + 4 * PTS + p];
        const float x = xyt[(gp0 + p) * 3 + 0];
        const float y = xyt[(gp0 + p) * 3 + 1];
        const float t = xyt[(gp0 + p) * 3 + 2];
        const float pi = 3.14159265358979323846f;
        const float f = sinf(pi * x) * sinf(pi * y) * expf(-t);
        // res = MU*ht - K*(h*lap + hx^2 + hy^2) - f, MU=1, K=0.5
        const float res = ht - 0.5f * (fmaf(h, lap, fmaf(hx, hx, hy * hy))) - f;
        out[gp0 + p] = res;
    }
}

extern "C" void kernel_launch(void* const* d_in, const int* in_sizes, int n_in,
                              void* d_out, int out_size, void* d_ws, size_t ws_size,
                              hipStream_t stream) {
    const float* xyt = (const float*)d_in[0];
    const float* w0  = (const float*)d_in[1];
    const float* b0  = (const float*)d_in[2];
    const float* w1  = (const float*)d_in[3];
    const float* b1  = (const float*)d_in[4];
    const float* w2  = (const float*)d_in[5];
    const float* b2  = (const float*)d_in[6];
    const float* w3  = (const float*)d_in[7];
    const float* b3  = (const float*)d_in[8];
    const float* w4  = (const float*)d_in[9];
    const float* b4  = (const float*)d_in[10];
    const float* w5  = (const float*)d_in[11];
    const float* b5  = (const float*)d_in[12];
    const float* w6  = (const float*)d_in[13];
    const float* b6  = (const float*)d_in[14];
    float* out = (float*)d_out;

    const int npts = in_sizes[0] / 3;   // 131072
    dim3 grid(npts / PTS);
    dim3 block(256);
    pde_net_kernel<<<grid, block, 0, stream>>>(xyt, w0, b0, w1, b1, w2, b2,
                                               w3, b3, w4, b4, w5, b5, w6, b6, out);
}

// Round 7
// 2184.460 us; speedup vs baseline: 3.0152x; 2.1060x over previous
//
#include <hip/hip_runtime.h>
#include <math.h>

#define WIDTH 256
#define PTS 16
#define NROW 80            // 5 vecs * 16 points
#define BSTR 264           // padded bf16 row stride (528 B): bank-even for b128 reads
#define ZCOMP (NROW * BSTR)

typedef short bf16x8 __attribute__((ext_vector_type(8)));
typedef short s16x4  __attribute__((ext_vector_type(4)));
typedef float f32x4  __attribute__((ext_vector_type(4)));

__device__ __forceinline__ float bf2f(unsigned short h) {
    return __uint_as_float(((unsigned)h) << 16);
}
// round-to-nearest-even fp32->bf16, returns exact fp32 residual
__device__ __forceinline__ unsigned short bf_rne(float f, float& rem) {
    unsigned u = __float_as_uint(f);
    unsigned r = u + 0x7FFFu + ((u >> 16) & 1u);
    unsigned short h = (unsigned short)(r >> 16);
    rem = f - bf2f(h);
    return h;
}
__device__ __forceinline__ void split3(float f, unsigned short& h, unsigned short& m,
                                       unsigned short& l) {
    float r1, r2, r3;
    h = bf_rne(f, r1);
    m = bf_rne(r1, r2);
    l = bf_rne(r2, r3);
}
// z=tanh(u), s=1-z^2 = 4t/(1+t)^2 with t=exp(-2|u|): no cancellation in saturation
__device__ __forceinline__ void tanh_s(float u, float& z, float& s) {
    const float t = __expf(-2.0f * fabsf(u));
    const float r = 1.0f / (1.0f + t);
    const float zm = (1.0f - t) * r;
    z = copysignf(zm, u);
    s = 4.0f * t * r * r;
}

// Pre-split w1..w5 into bf16 hi/mid/lo, transposed + packed in MFMA A-frag order:
// wt3[(l*3+c)*65536 + ((jt*8+kc)*64 + lane)*8 + i] = comp_c(W[k][j]),
// j = jt*16 + (lane&15), k = kc*32 + (lane>>4)*8 + i.
__global__ void prep_w_kernel(const float* __restrict__ w1, const float* __restrict__ w2,
                              const float* __restrict__ w3, const float* __restrict__ w4,
                              const float* __restrict__ w5, short* __restrict__ wt3)
{
    const int idx = blockIdx.x * blockDim.x + threadIdx.x;
    if (idx >= 5 * 16 * 8 * 64) return;
    const int lane = idx & 63;
    const int kc   = (idx >> 6) & 7;
    const int jt   = (idx >> 9) & 15;
    const int l    = idx >> 13;
    const float* Wsrc[5] = { w1, w2, w3, w4, w5 };
    const float* W = Wsrc[l];
    const int j  = jt * 16 + (lane & 15);
    const int k0 = kc * 32 + (lane >> 4) * 8;
    bf16x8 vh, vm, vl;
    #pragma unroll
    for (int i = 0; i < 8; ++i) {
        unsigned short h, m, lo;
        split3(W[(k0 + i) * WIDTH + j], h, m, lo);
        vh[i] = (short)h; vm[i] = (short)m; vl[i] = (short)lo;
    }
    const int fo = ((jt * 8 + kc) * 64 + lane) * 8;
    *(bf16x8*)(wt3 + (l * 3 + 0) * 65536 + fo) = vh;
    *(bf16x8*)(wt3 + (l * 3 + 1) * 65536 + fo) = vm;
    *(bf16x8*)(wt3 + (l * 3 + 2) * 65536 + fo) = vl;
}

__global__ __launch_bounds__(512, 2)
void pde_mfma_kernel(const float* __restrict__ xyt,
                     const float* __restrict__ w0, const float* __restrict__ b0,
                     const float* __restrict__ b1, const float* __restrict__ b2,
                     const float* __restrict__ b3, const float* __restrict__ b4,
                     const float* __restrict__ b5,
                     const float* __restrict__ w6, const float* __restrict__ b6,
                     const short* __restrict__ wt3,
                     float* __restrict__ out)
{
    // Z state as 3 bf16 component planes: Zs[c*ZCOMP + n*BSTR + k],
    // row n = v*16 + p (v = chain: z,zx,zy,zt,L), k = feature. 126720 B.
    __shared__ short Zs[3 * ZCOMP];
    __shared__ float red[NROW * 4 + NROW];

    const int tid = threadIdx.x;
    const long gp0 = (long)blockIdx.x * PTS;

    // ---------------- layer 0: (3 -> 256), Taylor-mode, fp32 VALU ----------
    {
        const int p  = tid & 15;
        const int jg = tid >> 4;            // 0..31 -> features jg*8..+7
        const float x = xyt[(gp0 + p) * 3 + 0];
        const float y = xyt[(gp0 + p) * 3 + 1];
        const float t = xyt[(gp0 + p) * 3 + 2];
        bf16x8 vh[5], vm[5], vl[5];
        #pragma unroll
        for (int c = 0; c < 8; ++c) {
            const int j = jg * 8 + c;
            const float wx = w0[0 * WIDTH + j];
            const float wy = w0[1 * WIDTH + j];
            const float wt = w0[2 * WIDTH + j];
            float zv, s;
            tanh_s(fmaf(x, wx, fmaf(y, wy, fmaf(t, wt, b0[j]))), zv, s);
            const float vals[5] = { zv, s * wx, s * wy, s * wt,
                                    -2.0f * zv * s * (wx * wx + wy * wy) };
            #pragma unroll
            for (int v = 0; v < 5; ++v) {
                unsigned short h, m, lo;
                split3(vals[v], h, m, lo);
                vh[v][c] = (short)h; vm[v][c] = (short)m; vl[v][c] = (short)lo;
            }
        }
        #pragma unroll
        for (int v = 0; v < 5; ++v) {
            const int ro = (v * 16 + p) * BSTR + jg * 8;
            *(bf16x8*)&Zs[0 * ZCOMP + ro] = vh[v];
            *(bf16x8*)&Zs[1 * ZCOMP + ro] = vm[v];
            *(bf16x8*)&Zs[2 * ZCOMP + ro] = vl[v];
        }
    }
    __syncthreads();

    // ---------------- hidden layers 1..5: MFMA bf16x3 (6-product) ----------
    const float* Bsl[5] = { b1, b2, b3, b4, b5 };
    const int lane = tid & 63;
    const int wv   = tid >> 6;       // wave 0..7 -> M-tiles {2w, 2w+1}
    const int q    = lane >> 4;      // quad
    const int n15  = lane & 15;

    for (int l = 0; l < 5; ++l) {
        const short* Wl = wt3 + l * 3 * 65536;
        f32x4 acc[5][2];
        #pragma unroll
        for (int v = 0; v < 5; ++v)
            #pragma unroll
            for (int Mt = 0; Mt < 2; ++Mt)
                acc[v][Mt] = (f32x4){0.f, 0.f, 0.f, 0.f};

        for (int kc = 0; kc < 8; ++kc) {
            bf16x8 A[2][3];
            #pragma unroll
            for (int Mt = 0; Mt < 2; ++Mt) {
                const int fo = (((wv * 2 + Mt) * 8 + kc) * 64 + lane) * 8;
                A[Mt][0] = *(const bf16x8*)(Wl + 0 * 65536 + fo);
                A[Mt][1] = *(const bf16x8*)(Wl + 1 * 65536 + fo);
                A[Mt][2] = *(const bf16x8*)(Wl + 2 * 65536 + fo);
            }
            #pragma unroll
            for (int v = 0; v < 5; ++v) {
                const int zo = (v * 16 + n15) * BSTR + kc * 32 + q * 8;
                const bf16x8 Bh = *(const bf16x8*)&Zs[0 * ZCOMP + zo];
                const bf16x8 Bm = *(const bf16x8*)&Zs[1 * ZCOMP + zo];
                const bf16x8 Bl = *(const bf16x8*)&Zs[2 * ZCOMP + zo];
                #pragma unroll
                for (int Mt = 0; Mt < 2; ++Mt) {
                    f32x4 a = acc[v][Mt];
                    a = __builtin_amdgcn_mfma_f32_16x16x32_bf16(A[Mt][0], Bh, a, 0, 0, 0);
                    a = __builtin_amdgcn_mfma_f32_16x16x32_bf16(A[Mt][0], Bm, a, 0, 0, 0);
                    a = __builtin_amdgcn_mfma_f32_16x16x32_bf16(A[Mt][1], Bh, a, 0, 0, 0);
                    a = __builtin_amdgcn_mfma_f32_16x16x32_bf16(A[Mt][0], Bl, a, 0, 0, 0);
                    a = __builtin_amdgcn_mfma_f32_16x16x32_bf16(A[Mt][1], Bm, a, 0, 0, 0);
                    a = __builtin_amdgcn_mfma_f32_16x16x32_bf16(A[Mt][2], Bh, a, 0, 0, 0);
                    acc[v][Mt] = a;
                }
            }
        }
        __syncthreads();   // all Zs reads done before overwrite

        // epilogue: lane holds (j = jt*16 + q*4 + reg, p = n15), all 5 chains
        const float* Bb = Bsl[l];
        #pragma unroll
        for (int Mt = 0; Mt < 2; ++Mt) {
            const int jt = wv * 2 + Mt;
            s16x4 oh[5], om[5], ol[5];
            #pragma unroll
            for (int reg = 0; reg < 4; ++reg) {
                const int j = jt * 16 + q * 4 + reg;
                float zv, s;
                tanh_s(acc[0][Mt][reg] + Bb[j], zv, s);
                const float u1 = acc[1][Mt][reg];
                const float u2 = acc[2][Mt][reg];
                const float nv[5] = { zv, s * u1, s * u2, s * acc[3][Mt][reg],
                                      fmaf(-2.0f * zv * s, fmaf(u1, u1, u2 * u2),
                                           s * acc[4][Mt][reg]) };
                #pragma unroll
                for (int v = 0; v < 5; ++v) {
                    unsigned short h, m, lo;
                    split3(nv[v], h, m, lo);
                    oh[v][reg] = (short)h; om[v][reg] = (short)m; ol[v][reg] = (short)lo;
                }
            }
            const int wb = jt * 16 + q * 4;
            #pragma unroll
            for (int v = 0; v < 5; ++v) {
                const int ro = (v * 16 + n15) * BSTR + wb;
                *(s16x4*)&Zs[0 * ZCOMP + ro] = oh[v];
                *(s16x4*)&Zs[1 * ZCOMP + ro] = om[v];
                *(s16x4*)&Zs[2 * ZCOMP + ro] = ol[v];
            }
        }
        __syncthreads();
    }

    // ---------------- final layer: (256 -> 1) dot products ------------------
    if (tid < 4 * NROW) {
        const int n  = tid >> 2;         // row 0..79
        const int kq = tid & 3;          // 64-feature chunk
        float sum = 0.f;
        const int ro = n * BSTR;
        for (int kk = kq * 64; kk < kq * 64 + 64; kk += 8) {
            const bf16x8 zh = *(const bf16x8*)&Zs[0 * ZCOMP + ro + kk];
            const bf16x8 zm = *(const bf16x8*)&Zs[1 * ZCOMP + ro + kk];
            const bf16x8 zl = *(const bf16x8*)&Zs[2 * ZCOMP + ro + kk];
            #pragma unroll
            for (int i = 0; i < 8; ++i) {
                const float zf = bf2f((unsigned short)zh[i]) +
                                 bf2f((unsigned short)zm[i]) +
                                 bf2f((unsigned short)zl[i]);
                sum = fmaf(zf, w6[kk + i], sum);
            }
        }
        red[kq * NROW + n] = sum;
    }
    __syncthreads();
    if (tid < NROW)
        red[4 * NROW + tid] = red[tid] + red[NROW + tid] + red[2 * NROW + tid] + red[3 * NROW + tid];
    __syncthreads();

    // ---------------- residual ----------------
    if (tid < PTS) {
        const int p = tid;
        const float* tot = red + 4 * NROW;
        const float h   = tot[0 * 16 + p] + b6[0];
        const float hx  = tot[1 * 16 + p];
        const float hy  = tot[2 * 16 + p];
        const float ht  = tot[3 * 16 + p];
        const float lap = tot[4 * 16 + p];
        const float x = xyt[(gp0 + p) * 3 + 0];
        const float y = xyt[(gp0 + p) * 3 + 1];
        const float t = xyt[(gp0 + p) * 3 + 2];
        const float pi = 3.14159265358979323846f;
        const float f = sinf(pi * x) * sinf(pi * y) * expf(-t);
        out[gp0 + p] = ht - 0.5f * (fmaf(h, lap, fmaf(hx, hx, hy * hy))) - f;
    }
}

extern "C" void kernel_launch(void* const* d_in, const int* in_sizes, int n_in,
                              void* d_out, int out_size, void* d_ws, size_t ws_size,
                              hipStream_t stream) {
    const float* xyt = (const float*)d_in[0];
    const float* w0  = (const float*)d_in[1];
    const float* b0  = (const float*)d_in[2];
    const float* w1  = (const float*)d_in[3];
    const float* b1  = (const float*)d_in[4];
    const float* w2  = (const float*)d_in[5];
    const float* b2  = (const float*)d_in[6];
    const float* w3  = (const float*)d_in[7];
    const float* b3  = (const float*)d_in[8];
    const float* w4  = (const float*)d_in[9];
    const float* b4  = (const float*)d_in[10];
    const float* w5  = (const float*)d_in[11];
    const float* b5  = (const float*)d_in[12];
    const float* w6  = (const float*)d_in[13];
    const float* b6  = (const float*)d_in[14];
    float* out = (float*)d_out;
    short* wt3 = (short*)d_ws;       // needs 5*3*65536*2 = 1,966,080 B

    prep_w_kernel<<<160, 256, 0, stream>>>(w1, w2, w3, w4, w5, wt3);

    const int npts = in_sizes[0] / 3;   // 131072
    dim3 grid(npts / PTS);              // 8192
    dim3 block(512);
    pde_mfma_kernel<<<grid, block, 0, stream>>>(xyt, w0, b0, b1, b2, b3, b4, b5,
                                                w6, b6, wt3, out);
}

// Round 8
// 1147.912 us; speedup vs baseline: 5.7379x; 1.9030x over previous
//
#include <hip/hip_runtime.h>
#include <math.h>

#define WIDTH 256
#define PTS 16
#define NROW 80            // 5 chains * 16 points
#define CPLANE 20480       // halves per component plane: 5v * 8kc * 64lane * 8

typedef _Float16 f16x8 __attribute__((ext_vector_type(8)));
typedef _Float16 f16x4 __attribute__((ext_vector_type(4)));
typedef float    f32x4 __attribute__((ext_vector_type(4)));

// fp32 -> fp16 hi + fp16 lo (2-split, covers ~22-24 mantissa bits)
__device__ __forceinline__ void split2(float f, _Float16& h, _Float16& l) {
    h = (_Float16)f;
    l = (_Float16)(f - (float)h);
}
// z=tanh(u), s=1-z^2 = 4t/(1+t)^2 with t=exp(-2|u|): no cancellation in saturation
__device__ __forceinline__ void tanh_s(float u, float& z, float& s) {
    const float t = __expf(-2.0f * fabsf(u));
    const float r = 1.0f / (1.0f + t);
    const float zm = (1.0f - t) * r;
    z = copysignf(zm, u);
    s = 4.0f * t * r * r;
}

// Pre-split w1..w5 into fp16 hi/lo, transposed + packed in MFMA A-frag order:
// wt2[(l*2+c)*65536 + ((jt*8+kc)*64 + lane)*8 + i] = comp_c(W[k][j]),
// j = jt*16 + (lane&15), k = kc*32 + (lane>>4)*8 + i.
__global__ void prep_w_kernel(const float* __restrict__ w1, const float* __restrict__ w2,
                              const float* __restrict__ w3, const float* __restrict__ w4,
                              const float* __restrict__ w5, _Float16* __restrict__ wt2)
{
    const int idx = blockIdx.x * blockDim.x + threadIdx.x;
    if (idx >= 5 * 16 * 8 * 64) return;
    const int lane = idx & 63;
    const int kc   = (idx >> 6) & 7;
    const int jt   = (idx >> 9) & 15;
    const int l    = idx >> 13;
    const float* Wsrc[5] = { w1, w2, w3, w4, w5 };
    const float* W = Wsrc[l];
    const int j  = jt * 16 + (lane & 15);
    const int k0 = kc * 32 + (lane >> 4) * 8;
    f16x8 vh, vl;
    #pragma unroll
    for (int i = 0; i < 8; ++i) {
        _Float16 h, lo;
        split2(W[(k0 + i) * WIDTH + j], h, lo);
        vh[i] = h; vl[i] = lo;
    }
    const int fo = ((jt * 8 + kc) * 64 + lane) * 8;
    *(f16x8*)(wt2 + (l * 2 + 0) * 65536 + fo) = vh;
    *(f16x8*)(wt2 + (l * 2 + 1) * 65536 + fo) = vl;
}

__global__ __launch_bounds__(256, 2)
void pde_mfma_kernel(const float* __restrict__ xyt,
                     const float* __restrict__ w0, const float* __restrict__ b0,
                     const float* __restrict__ b1, const float* __restrict__ b2,
                     const float* __restrict__ b3, const float* __restrict__ b4,
                     const float* __restrict__ b5,
                     const float* __restrict__ w6, const float* __restrict__ b6,
                     const _Float16* __restrict__ wt2,
                     float* __restrict__ out)
{
    // Z in B-frag consumption order: Zs[c*CPLANE + ((v*8+kc)*64 + lane)*8 + i]
    // holds Z[row n = lane&15 (point), k = kc*32 + (lane>>4)*8 + i] of chain v.
    // k-loop reads are lane*16B contiguous -> conflict-free (m134 pattern).
    // 2 comps * 20480 halves * 2 B = 81920 B exactly -> 2 blocks/CU.
    __shared__ _Float16 Zs[2 * CPLANE];
    float* redf = (float*)Zs;         // aliased reduction scratch (after last Z read)

    const int tid = threadIdx.x;
    const long gp0 = (long)blockIdx.x * PTS;

    // ---------------- layer 0: (3 -> 256), Taylor-mode, fp32 VALU ----------
    {
        const int p = tid & 15;
        const float x = xyt[(gp0 + p) * 3 + 0];
        const float y = xyt[(gp0 + p) * 3 + 1];
        const float t = xyt[(gp0 + p) * 3 + 2];
        #pragma unroll
        for (int half = 0; half < 2; ++half) {
            const int jg = (tid >> 4) + half * 16;   // 0..31, 8 features each
            f16x8 vh[5], vl[5];
            #pragma unroll
            for (int c = 0; c < 8; ++c) {
                const int j = jg * 8 + c;
                const float wx = w0[0 * WIDTH + j];
                const float wy = w0[1 * WIDTH + j];
                const float wt = w0[2 * WIDTH + j];
                float zv, s;
                tanh_s(fmaf(x, wx, fmaf(y, wy, fmaf(t, wt, b0[j]))), zv, s);
                const float vals[5] = { zv, s * wx, s * wy, s * wt,
                                        -2.0f * zv * s * (wx * wx + wy * wy) };
                #pragma unroll
                for (int v = 0; v < 5; ++v) {
                    _Float16 h, lo;
                    split2(vals[v], h, lo);
                    vh[v][c] = h; vl[v][c] = lo;
                }
            }
            // j block jg*8..+7: kc = jg>>2, q' = jg&3, i = c
            #pragma unroll
            for (int v = 0; v < 5; ++v) {
                const int off = ((v * 8 + (jg >> 2)) * 64 + (jg & 3) * 16 + p) * 8;
                *(f16x8*)&Zs[0 * CPLANE + off] = vh[v];
                *(f16x8*)&Zs[1 * CPLANE + off] = vl[v];
            }
        }
    }
    __syncthreads();

    // ---------------- hidden layers 1..5: MFMA fp16 2-split (3 products) ----
    const float* Bsl[5] = { b1, b2, b3, b4, b5 };
    const int lane = tid & 63;
    const int wv   = tid >> 6;       // wave 0..3 -> M-tiles 4w..4w+3
    const int q    = lane >> 4;
    const int n15  = lane & 15;

    for (int l = 0; l < 5; ++l) {
        const _Float16* Wl = wt2 + l * 2 * 65536;
        f32x4 acc[5][4];
        #pragma unroll
        for (int v = 0; v < 5; ++v)
            #pragma unroll
            for (int Mt = 0; Mt < 4; ++Mt)
                acc[v][Mt] = (f32x4){0.f, 0.f, 0.f, 0.f};

        #pragma unroll 1
        for (int kc = 0; kc < 8; ++kc) {
            f16x8 Ah[4], Al[4];
            #pragma unroll
            for (int Mt = 0; Mt < 4; ++Mt) {
                const int fo = (((wv * 4 + Mt) * 8 + kc) * 64 + lane) * 8;
                Ah[Mt] = *(const f16x8*)(Wl + fo);
                Al[Mt] = *(const f16x8*)(Wl + 65536 + fo);
            }
            #pragma unroll
            for (int v = 0; v < 5; ++v) {
                const int zo = ((v * 8 + kc) * 64 + lane) * 8;
                const f16x8 Bh = *(const f16x8*)&Zs[0 * CPLANE + zo];
                const f16x8 Bl = *(const f16x8*)&Zs[1 * CPLANE + zo];
                #pragma unroll
                for (int Mt = 0; Mt < 4; ++Mt) {
                    f32x4 a = acc[v][Mt];
                    a = __builtin_amdgcn_mfma_f32_16x16x32_f16(Ah[Mt], Bl, a, 0, 0, 0);
                    a = __builtin_amdgcn_mfma_f32_16x16x32_f16(Al[Mt], Bh, a, 0, 0, 0);
                    a = __builtin_amdgcn_mfma_f32_16x16x32_f16(Ah[Mt], Bh, a, 0, 0, 0);
                    acc[v][Mt] = a;
                }
            }
        }
        __syncthreads();   // all Zs reads done before overwrite

        // epilogue: lane holds (j = jt*16 + q*4 + reg, p = n15), all 5 chains
        const float* Bb = Bsl[l];
        #pragma unroll
        for (int Mt = 0; Mt < 4; ++Mt) {
            const int jt = wv * 4 + Mt;
            f16x4 oh[5], ol[5];
            #pragma unroll
            for (int reg = 0; reg < 4; ++reg) {
                const int j = jt * 16 + q * 4 + reg;
                float zv, s;
                tanh_s(acc[0][Mt][reg] + Bb[j], zv, s);
                const float u1 = acc[1][Mt][reg];
                const float u2 = acc[2][Mt][reg];
                const float nv[5] = { zv, s * u1, s * u2, s * acc[3][Mt][reg],
                                      fmaf(-2.0f * zv * s, fmaf(u1, u1, u2 * u2),
                                           s * acc[4][Mt][reg]) };
                #pragma unroll
                for (int v = 0; v < 5; ++v) {
                    _Float16 h, lo;
                    split2(nv[v], h, lo);
                    oh[v][reg] = h; ol[v][reg] = lo;
                }
            }
            // j0 = jt*16 + q*4 -> kc' = j0>>5, q'' = (j0>>3)&3, i0 = (q&1)*4
            const int j0 = jt * 16 + q * 4;
            const int off0 = ((j0 >> 5) * 64 + ((j0 >> 3) & 3) * 16 + n15) * 8 + (j0 & 7);
            #pragma unroll
            for (int v = 0; v < 5; ++v) {
                *(f16x4*)&Zs[0 * CPLANE + v * 4096 + off0] = oh[v];
                *(f16x4*)&Zs[1 * CPLANE + v * 4096 + off0] = ol[v];
            }
        }
        __syncthreads();
    }

    // ---------------- final layer: (256 -> 1) dot products ------------------
    // 80 rows x 2 halves of 128 features; 160 active threads.
    float partial = 0.f;
    const int n    = tid >> 1;        // row 0..79 (valid if tid < 160)
    const int half = tid & 1;
    if (tid < 2 * NROW) {
        const int v = n >> 4, p = n & 15;
        for (int kk = half * 128; kk < half * 128 + 128; kk += 8) {
            const int off = ((v * 8 + (kk >> 5)) * 64 + ((kk >> 3) & 3) * 16 + p) * 8;
            const f16x8 zh = *(const f16x8*)&Zs[0 * CPLANE + off];
            const f16x8 zl = *(const f16x8*)&Zs[1 * CPLANE + off];
            #pragma unroll
            for (int i = 0; i < 8; ++i)
                partial = fmaf((float)zh[i] + (float)zl[i], w6[kk + i], partial);
        }
    }
    __syncthreads();                 // all reads of Zs done before aliasing
    if (tid < 2 * NROW) redf[half * NROW + n] = partial;
    __syncthreads();
    if (tid < NROW) redf[2 * NROW + tid] = redf[tid] + redf[NROW + tid];
    __syncthreads();

    // ---------------- residual ----------------
    if (tid < PTS) {
        const int p = tid;
        const float* tot = redf + 2 * NROW;
        const float h   = tot[0 * 16 + p] + b6[0];
        const float hx  = tot[1 * 16 + p];
        const float hy  = tot[2 * 16 + p];
        const float ht  = tot[3 * 16 + p];
        const float lap = tot[4 * 16 + p];
        const float x = xyt[(gp0 + p) * 3 + 0];
        const float y = xyt[(gp0 + p) * 3 + 1];
        const float t = xyt[(gp0 + p) * 3 + 2];
        const float pi = 3.14159265358979323846f;
        const float f = sinf(pi * x) * sinf(pi * y) * expf(-t);
        out[gp0 + p] = ht - 0.5f * (fmaf(h, lap, fmaf(hx, hx, hy * hy))) - f;
    }
}

extern "C" void kernel_launch(void* const* d_in, const int* in_sizes, int n_in,
                              void* d_out, int out_size, void* d_ws, size_t ws_size,
                              hipStream_t stream) {
    const float* xyt = (const float*)d_in[0];
    const float* w0  = (const float*)d_in[1];
    const float* b0  = (const float*)d_in[2];
    const float* w1  = (const float*)d_in[3];
    const float* b1  = (const float*)d_in[4];
    const float* w2  = (const float*)d_in[5];
    const float* b2  = (const float*)d_in[6];
    const float* w3  = (const float*)d_in[7];
    const float* b3  = (const float*)d_in[8];
    const float* w4  = (const float*)d_in[9];
    const float* b4  = (const float*)d_in[10];
    const float* w5  = (const float*)d_in[11];
    const float* b5  = (const float*)d_in[12];
    const float* w6  = (const float*)d_in[13];
    const float* b6  = (const float*)d_in[14];
    float* out = (float*)d_out;
    _Float16* wt2 = (_Float16*)d_ws;    // needs 5*2*65536*2 = 1,310,720 B

    prep_w_kernel<<<160, 256, 0, stream>>>(w1, w2, w3, w4, w5, wt2);

    const int npts = in_sizes[0] / 3;   // 131072
    dim3 grid(npts / PTS);              // 8192
    dim3 block(256);
    pde_mfma_kernel<<<grid, block, 0, stream>>>(xyt, w0, b0, b1, b2, b3, b4, b5,
                                                w6, b6, wt2, out);
}

// Round 10
// 1112.934 us; speedup vs baseline: 5.9182x; 1.0314x over previous
//
#include <hip/hip_runtime.h>
#include <math.h>

#define WIDTH 256
#define PTS 16
#define NROW 80            // 5 chains * 16 points
#define CPLANE 20480       // halves per component plane: 5v * 8kc * 64lane * 8

typedef _Float16 f16x8 __attribute__((ext_vector_type(8)));
typedef _Float16 f16x4 __attribute__((ext_vector_type(4)));
typedef __fp16   h16x2 __attribute__((ext_vector_type(2)));   // cvt_pkrtz return type
typedef float    f32x4 __attribute__((ext_vector_type(4)));

// fp32 -> fp16 hi + fp16 lo (2-split, covers ~22-24 mantissa bits)
__device__ __forceinline__ void split2(float f, _Float16& h, _Float16& l) {
    h = (_Float16)f;
    l = (_Float16)(f - (float)h);
}
// z=tanh(u), s=1-z^2 = 4t/(1+t)^2 with t=exp(-2|u|): no cancellation in saturation
__device__ __forceinline__ void tanh_s(float u, float& z, float& s) {
    const float t = __expf(-2.0f * fabsf(u));
    const float r = 1.0f / (1.0f + t);
    const float zm = (1.0f - t) * r;
    z = copysignf(zm, u);
    s = 4.0f * t * r * r;
}

// Pre-split w1..w5 into fp16 hi/lo, transposed + packed in MFMA A-frag order:
// wt2[(l*2+c)*65536 + ((jt*8+kc)*64 + lane)*8 + i] = comp_c(W[k][j]),
// j = jt*16 + (lane&15), k = kc*32 + (lane>>4)*8 + i.
__global__ void prep_w_kernel(const float* __restrict__ w1, const float* __restrict__ w2,
                              const float* __restrict__ w3, const float* __restrict__ w4,
                              const float* __restrict__ w5, _Float16* __restrict__ wt2)
{
    const int idx = blockIdx.x * blockDim.x + threadIdx.x;
    if (idx >= 5 * 16 * 8 * 64) return;
    const int lane = idx & 63;
    const int kc   = (idx >> 6) & 7;
    const int jt   = (idx >> 9) & 15;
    const int l    = idx >> 13;
    const float* Wsrc[5] = { w1, w2, w3, w4, w5 };
    const float* W = Wsrc[l];
    const int j  = jt * 16 + (lane & 15);
    const int k0 = kc * 32 + (lane >> 4) * 8;
    f16x8 vh, vl;
    #pragma unroll
    for (int i = 0; i < 8; ++i) {
        _Float16 h, lo;
        split2(W[(k0 + i) * WIDTH + j], h, lo);
        vh[i] = h; vl[i] = lo;
    }
    const int fo = ((jt * 8 + kc) * 64 + lane) * 8;
    *(f16x8*)(wt2 + (l * 2 + 0) * 65536 + fo) = vh;
    *(f16x8*)(wt2 + (l * 2 + 1) * 65536 + fo) = vl;
}

__global__ __launch_bounds__(256, 2)
void pde_mfma_kernel(const float* __restrict__ xyt,
                     const float* __restrict__ w0, const float* __restrict__ b0,
                     const float* __restrict__ b1, const float* __restrict__ b2,
                     const float* __restrict__ b3, const float* __restrict__ b4,
                     const float* __restrict__ b5,
                     const float* __restrict__ w6, const float* __restrict__ b6,
                     const _Float16* __restrict__ wt2,
                     float* __restrict__ out)
{
    // Z in B-frag consumption order: Zs[c*CPLANE + ((v*8+kc)*64 + lane)*8 + i]
    // holds Z[row n = lane&15 (point), k = kc*32 + (lane>>4)*8 + i] of chain v.
    // k-loop reads are lane*16B contiguous -> conflict-free.
    // 2 comps * 20480 halves * 2 B = 81920 B exactly -> 2 blocks/CU.
    __shared__ _Float16 Zs[2 * CPLANE];
    float* redf = (float*)Zs;         // aliased reduction scratch (after last Z read)

    const int tid = threadIdx.x;
    const long gp0 = (long)blockIdx.x * PTS;

    // ---------------- layer 0: (3 -> 256), Taylor-mode, fp32 VALU ----------
    {
        const int p = tid & 15;
        const float x = xyt[(gp0 + p) * 3 + 0];
        const float y = xyt[(gp0 + p) * 3 + 1];
        const float t = xyt[(gp0 + p) * 3 + 2];
        #pragma unroll
        for (int half = 0; half < 2; ++half) {
            const int jg = (tid >> 4) + half * 16;   // 0..31, 8 features each
            f16x8 vh[5], vl[5];
            #pragma unroll
            for (int c = 0; c < 8; ++c) {
                const int j = jg * 8 + c;
                const float wx = w0[0 * WIDTH + j];
                const float wy = w0[1 * WIDTH + j];
                const float wt = w0[2 * WIDTH + j];
                float zv, s;
                tanh_s(fmaf(x, wx, fmaf(y, wy, fmaf(t, wt, b0[j]))), zv, s);
                const float vals[5] = { zv, s * wx, s * wy, s * wt,
                                        -2.0f * zv * s * (wx * wx + wy * wy) };
                #pragma unroll
                for (int v = 0; v < 5; ++v) {
                    _Float16 h, lo;
                    split2(vals[v], h, lo);
                    vh[v][c] = h; vl[v][c] = lo;
                }
            }
            // j block jg*8..+7: kc = jg>>2, q' = jg&3, i = c
            #pragma unroll
            for (int v = 0; v < 5; ++v) {
                const int off = ((v * 8 + (jg >> 2)) * 64 + (jg & 3) * 16 + p) * 8;
                *(f16x8*)&Zs[0 * CPLANE + off] = vh[v];
                *(f16x8*)&Zs[1 * CPLANE + off] = vl[v];
            }
        }
    }
    __syncthreads();

    // ---------------- hidden layers 1..5: MFMA fp16 2-split (3 products) ----
    const float* Bsl[5] = { b1, b2, b3, b4, b5 };
    const int lane = tid & 63;
    const int wv   = tid >> 6;       // wave 0..3 -> M-tiles 4w..4w+3
    const int q    = lane >> 4;
    const int n15  = lane & 15;

    for (int l = 0; l < 5; ++l) {
        const _Float16* Wl = wt2 + l * 2 * 65536;
        f32x4 acc[5][4];
        #pragma unroll
        for (int v = 0; v < 5; ++v)
            #pragma unroll
            for (int Mt = 0; Mt < 4; ++Mt)
                acc[v][Mt] = (f32x4){0.f, 0.f, 0.f, 0.f};

        // unroll 2: allows cross-kc prefetch of A/B frags (VGPR budget 256 @ 2 waves/SIMD)
        #pragma unroll 2
        for (int kc = 0; kc < 8; ++kc) {
            f16x8 Ah[4], Al[4];
            #pragma unroll
            for (int Mt = 0; Mt < 4; ++Mt) {
                const int fo = (((wv * 4 + Mt) * 8 + kc) * 64 + lane) * 8;
                Ah[Mt] = *(const f16x8*)(Wl + fo);
                Al[Mt] = *(const f16x8*)(Wl + 65536 + fo);
            }
            #pragma unroll
            for (int v = 0; v < 5; ++v) {
                const int zo = ((v * 8 + kc) * 64 + lane) * 8;
                const f16x8 Bh = *(const f16x8*)&Zs[0 * CPLANE + zo];
                const f16x8 Bl = *(const f16x8*)&Zs[1 * CPLANE + zo];
                #pragma unroll
                for (int Mt = 0; Mt < 4; ++Mt) {
                    f32x4 a = acc[v][Mt];
                    a = __builtin_amdgcn_mfma_f32_16x16x32_f16(Ah[Mt], Bl, a, 0, 0, 0);
                    a = __builtin_amdgcn_mfma_f32_16x16x32_f16(Al[Mt], Bh, a, 0, 0, 0);
                    a = __builtin_amdgcn_mfma_f32_16x16x32_f16(Ah[Mt], Bh, a, 0, 0, 0);
                    acc[v][Mt] = a;
                }
            }
        }
        __syncthreads();   // all Zs reads done before overwrite

        // epilogue: lane holds (j = jt*16 + q*4 + reg, p = n15), all 5 chains
        const float* Bb = Bsl[l];
        #pragma unroll
        for (int Mt = 0; Mt < 4; ++Mt) {
            const int jt = wv * 4 + Mt;
            float nv[5][4];
            #pragma unroll
            for (int reg = 0; reg < 4; ++reg) {
                const int j = jt * 16 + q * 4 + reg;
                float zv, s;
                tanh_s(acc[0][Mt][reg] + Bb[j], zv, s);
                const float u1 = acc[1][Mt][reg];
                const float u2 = acc[2][Mt][reg];
                nv[0][reg] = zv;
                nv[1][reg] = s * u1;
                nv[2][reg] = s * u2;
                nv[3][reg] = s * acc[3][Mt][reg];
                nv[4][reg] = fmaf(-2.0f * zv * s, fmaf(u1, u1, u2 * u2),
                                  s * acc[4][Mt][reg]);
            }
            // j0 = jt*16 + q*4 -> kc' = j0>>5, q'' = (j0>>3)&3, i0 = j0&7
            const int j0 = jt * 16 + q * 4;
            const int off0 = ((j0 >> 5) * 64 + ((j0 >> 3) & 3) * 16 + n15) * 8 + (j0 & 7);
            #pragma unroll
            for (int v = 0; v < 5; ++v) {
                // packed hi (RTZ) + exact lo remainders, packed
                const h16x2 h01 = __builtin_amdgcn_cvt_pkrtz(nv[v][0], nv[v][1]);
                const h16x2 h23 = __builtin_amdgcn_cvt_pkrtz(nv[v][2], nv[v][3]);
                const h16x2 l01 = __builtin_amdgcn_cvt_pkrtz(nv[v][0] - (float)h01[0],
                                                             nv[v][1] - (float)h01[1]);
                const h16x2 l23 = __builtin_amdgcn_cvt_pkrtz(nv[v][2] - (float)h23[0],
                                                             nv[v][3] - (float)h23[1]);
                *(f16x4*)&Zs[0 * CPLANE + v * 4096 + off0] =
                    (f16x4){ (_Float16)h01[0], (_Float16)h01[1],
                             (_Float16)h23[0], (_Float16)h23[1] };
                *(f16x4*)&Zs[1 * CPLANE + v * 4096 + off0] =
                    (f16x4){ (_Float16)l01[0], (_Float16)l01[1],
                             (_Float16)l23[0], (_Float16)l23[1] };
            }
        }
        __syncthreads();
    }

    // ---------------- final layer: (256 -> 1) dot products ------------------
    // 80 rows x 2 halves of 128 features; 160 active threads.
    float partial = 0.f;
    const int n    = tid >> 1;        // row 0..79 (valid if tid < 160)
    const int half = tid & 1;
    if (tid < 2 * NROW) {
        const int v = n >> 4, p = n & 15;
        for (int kk = half * 128; kk < half * 128 + 128; kk += 8) {
            const int off = ((v * 8 + (kk >> 5)) * 64 + ((kk >> 3) & 3) * 16 + p) * 8;
            const f16x8 zh = *(const f16x8*)&Zs[0 * CPLANE + off];
            const f16x8 zl = *(const f16x8*)&Zs[1 * CPLANE + off];
            #pragma unroll
            for (int i = 0; i < 8; ++i)
                partial = fmaf((float)zh[i] + (float)zl[i], w6[kk + i], partial);
        }
    }
    __syncthreads();                 // all reads of Zs done before aliasing
    if (tid < 2 * NROW) redf[half * NROW + n] = partial;
    __syncthreads();
    if (tid < NROW) redf[2 * NROW + tid] = redf[tid] + redf[NROW + tid];
    __syncthreads();

    // ---------------- residual ----------------
    if (tid < PTS) {
        const int p = tid;
        const float* tot = redf + 2 * NROW;
        const float h   = tot[0 * 16 + p] + b6[0];
        const float hx  = tot[1 * 16 + p];
        const float hy  = tot[2 * 16 + p];
        const float ht  = tot[3 * 16 + p];
        const float lap = tot[4 * 16 + p];
        const float x = xyt[(gp0 + p) * 3 + 0];
        const float y = xyt[(gp0 + p) * 3 + 1];
        const float t = xyt[(gp0 + p) * 3 + 2];
        const float pi = 3.14159265358979323846f;
        const float f = sinf(pi * x) * sinf(pi * y) * expf(-t);
        out[gp0 + p] = ht - 0.5f * (fmaf(h, lap, fmaf(hx, hx, hy * hy))) - f;
    }
}

extern "C" void kernel_launch(void* const* d_in, const int* in_sizes, int n_in,
                              void* d_out, int out_size, void* d_ws, size_t ws_size,
                              hipStream_t stream) {
    const float* xyt = (const float*)d_in[0];
    const float* w0  = (const float*)d_in[1];
    const float* b0  = (const float*)d_in[2];
    const float* w1  = (const float*)d_in[3];
    const float* b1  = (const float*)d_in[4];
    const float* w2  = (const float*)d_in[5];
    const float* b2  = (const float*)d_in[6];
    const float* w3  = (const float*)d_in[7];
    const float* b3  = (const float*)d_in[8];
    const float* w4  = (const float*)d_in[9];
    const float* b4  = (const float*)d_in[10];
    const float* w5  = (const float*)d_in[11];
    const float* b5  = (const float*)d_in[12];
    const float* w6  = (const float*)d_in[13];
    const float* b6  = (const float*)d_in[14];
    float* out = (float*)d_out;
    _Float16* wt2 = (_Float16*)d_ws;    // needs 5*2*65536*2 = 1,310,720 B

    prep_w_kernel<<<160, 256, 0, stream>>>(w1, w2, w3, w4, w5, wt2);

    const int npts = in_sizes[0] / 3;   // 131072
    dim3 grid(npts / PTS);              // 8192
    dim3 block(256);
    pde_mfma_kernel<<<grid, block, 0, stream>>>(xyt, w0, b0, b1, b2, b3, b4, b5,
                                                w6, b6, wt2, out);
}